// Round 1
// baseline (35.760 us; speedup 1.0000x reference)
//
#include <hip/hip_runtime.h>
#include <hip/hip_bf16.h>

#define BN_EPS 1e-5f

typedef float f32x4 __attribute__((ext_vector_type(4)));

// Dims (fixed by the problem): batch=1024, P=64, B=16, H=64, E=64,
// D0 = H+E = 128, D1 = 512, D2 = 1024.
//
// Dead code eliminated per analysis: softmax over singleton axis -> aw == 1,
// so the whole attention MLP (att1/att2/ws/end_pos) and velocity embedding
// are unused, and the output is i-independent within each group of P rows.

// ---------------------------------------------------------------------------
// k1: p1[r, c] = relu(bn1( x[r] @ W1 + b1 )),  x[r] = 0.05 * [h[r], at[r]*S + wa_b]
// grid 256 blocks (4 rows each), 256 threads (2 cols each)
// ---------------------------------------------------------------------------
__global__ __launch_bounds__(256) void k1_p1(
    const float* __restrict__ h,      // [1024,64]
    const float* __restrict__ at,     // agent_type[0] -> [1024]
    const float* __restrict__ wa_w,   // [6,64]
    const float* __restrict__ wa_b,   // [64]
    const float* __restrict__ w1,     // [128,512]
    const float* __restrict__ b1,     // [512]
    const float* __restrict__ bn1,    // [4,512] gamma,beta,mean,var
    float* __restrict__ p1)           // [1024,512]
{
    __shared__ float x[4][128];
    const int r0 = blockIdx.x * 4;
    const int t  = threadIdx.x;

    for (int idx = t; idx < 512; idx += 256) {
        const int rr = idx >> 7;
        const int k  = idx & 127;
        float v;
        if (k < 64) {
            v = h[(r0 + rr) * 64 + k];
        } else {
            const int e = k - 64;
            const float S = wa_w[e] + wa_w[64 + e] + wa_w[128 + e] +
                            wa_w[192 + e] + wa_w[256 + e] + wa_w[320 + e];
            v = at[r0 + rr] * S + wa_b[e];
        }
        x[rr][k] = 0.05f * v;
    }
    __syncthreads();

    float acc0[4] = {0.f, 0.f, 0.f, 0.f};
    float acc1[4] = {0.f, 0.f, 0.f, 0.f};
    #pragma unroll 4
    for (int k = 0; k < 128; ++k) {
        const float w0 = w1[k * 512 + t];
        const float wB = w1[k * 512 + t + 256];
        #pragma unroll
        for (int rr = 0; rr < 4; ++rr) {
            const float xv = x[rr][k];
            acc0[rr] = fmaf(xv, w0, acc0[rr]);
            acc1[rr] = fmaf(xv, wB, acc1[rr]);
        }
    }

    #pragma unroll
    for (int which = 0; which < 2; ++which) {
        const int c = t + which * 256;
        const float g  = bn1[c];
        const float be = bn1[512 + c];
        const float mu = bn1[1024 + c];
        const float vr = bn1[1536 + c];
        const float s  = rsqrtf(vr + BN_EPS) * g;
        const float bias = b1[c];
        const float* acc = which ? acc1 : acc0;
        #pragma unroll
        for (int rr = 0; rr < 4; ++rr) {
            const float val = (acc[rr] + bias - mu) * s + be;
            p1[(r0 + rr) * 512 + c] = fmaxf(val, 0.0f);
        }
    }
}

// ---------------------------------------------------------------------------
// k2: p2 = relu(bn2(p1 @ W2 + b2)); pool[b,c] = max_j p2[b,j,c];
//     out[b*64+i, c] = pool[b,c] for all i.
// grid (cc=16, b=16), 256 threads, 4x4 register tile, K-tile 64.
// ---------------------------------------------------------------------------
__global__ __launch_bounds__(256) void k2_p2_pool(
    const float* __restrict__ p1,   // [1024,512]
    const float* __restrict__ w2,   // [512,1024]
    const float* __restrict__ b2,   // [1024]
    const float* __restrict__ bn2,  // [4,1024]
    float* __restrict__ out)        // [1024,1024]
{
    const int cc = blockIdx.x;   // column chunk: 64 cols
    const int b  = blockIdx.y;   // group
    const int t  = threadIdx.x;

    __shared__ float A[64][68];        // p1 tile [row][k], pad 68 -> conflict-free
    __shared__ float Bm[64][64];       // w2 tile [k][c]
    __shared__ float red[16][64];      // row-group partial maxes

    const int rq = t >> 4;       // 0..15 row group
    const int cq = t & 15;       // 0..15 col group
    const int j0 = rq * 4;
    const int c0 = cq * 4;

    float acc[4][4] = {};

    for (int kt = 0; kt < 512; kt += 64) {
        #pragma unroll
        for (int i = 0; i < 4; ++i) {
            const int u   = t + i * 256;
            const int row = u >> 4;
            const int kq  = (u & 15) * 4;
            *(f32x4*)&A[row][kq] =
                *(const f32x4*)&p1[(b * 64 + row) * 512 + kt + kq];
        }
        #pragma unroll
        for (int i = 0; i < 4; ++i) {
            const int u   = t + i * 256;
            const int kk  = u >> 4;
            const int cq4 = (u & 15) * 4;
            *(f32x4*)&Bm[kk][cq4] =
                *(const f32x4*)&w2[(kt + kk) * 1024 + cc * 64 + cq4];
        }
        __syncthreads();

        #pragma unroll
        for (int k4 = 0; k4 < 16; ++k4) {
            f32x4 aj[4];
            #pragma unroll
            for (int jj = 0; jj < 4; ++jj)
                aj[jj] = *(const f32x4*)&A[j0 + jj][k4 * 4];
            f32x4 bk[4];
            #pragma unroll
            for (int u = 0; u < 4; ++u)
                bk[u] = *(const f32x4*)&Bm[k4 * 4 + u][c0];
            #pragma unroll
            for (int jj = 0; jj < 4; ++jj)
                #pragma unroll
                for (int u = 0; u < 4; ++u)
                    #pragma unroll
                    for (int ci = 0; ci < 4; ++ci)
                        acc[jj][ci] = fmaf(aj[jj][u], bk[u][ci], acc[jj][ci]);
        }
        __syncthreads();
    }

    // bias + bn2 + relu + per-thread max over its 4 rows
    f32x4 m4;
    #pragma unroll
    for (int ci = 0; ci < 4; ++ci) {
        const int c = cc * 64 + c0 + ci;
        const float g  = bn2[c];
        const float be = bn2[1024 + c];
        const float mu = bn2[2048 + c];
        const float vr = bn2[3072 + c];
        const float s  = rsqrtf(vr + BN_EPS) * g;
        const float bias = b2[c];
        float mm = 0.0f;   // relu outputs are >= 0
        #pragma unroll
        for (int jj = 0; jj < 4; ++jj) {
            float val = (acc[jj][ci] + bias - mu) * s + be;
            val = fmaxf(val, 0.0f);
            mm = fmaxf(mm, val);
        }
        m4[ci] = mm;
    }
    *(f32x4*)&red[rq][c0] = m4;
    __syncthreads();

    // final reduce over 16 row groups + broadcast store to all 64 i-rows
    const int c = t & 63;
    const int q = t >> 6;
    float pool = 0.0f;
    #pragma unroll
    for (int rr = 0; rr < 16; ++rr)
        pool = fmaxf(pool, red[rr][c]);
    const int obase = (b * 64) * 1024 + cc * 64 + c;
    #pragma unroll
    for (int i = q * 16; i < q * 16 + 16; ++i)
        out[obase + i * 1024] = pool;
}

extern "C" void kernel_launch(void* const* d_in, const int* in_sizes, int n_in,
                              void* d_out, int out_size, void* d_ws, size_t ws_size,
                              hipStream_t stream) {
    const float* h    = (const float*)d_in[0];   // h_states  [1,1024,64]
    const float* at   = (const float*)d_in[4];   // agent_type[8,1024,1] (slice 0 used)
    const float* wa_w = (const float*)d_in[9];   // [6,64]
    const float* wa_b = (const float*)d_in[10];  // [64]
    const float* w1   = (const float*)d_in[17];  // pre1_w [128,512]
    const float* b1   = (const float*)d_in[18];  // pre1_b [512]
    const float* bn1  = (const float*)d_in[19];  // pre_bn1 [4,512]
    const float* w2   = (const float*)d_in[20];  // pre2_w [512,1024]
    const float* b2   = (const float*)d_in[21];  // pre2_b [1024]
    const float* bn2  = (const float*)d_in[22];  // pre_bn2 [4,1024]

    float* p1  = (float*)d_ws;                   // needs 1024*512*4 = 2 MB
    float* out = (float*)d_out;

    k1_p1<<<256, 256, 0, stream>>>(h, at, wa_w, wa_b, w1, b1, bn1, p1);
    k2_p2_pool<<<dim3(16, 16), 256, 0, stream>>>(p1, w2, b2, bn2, out);
}

// Round 2
// 21.526 us; speedup vs baseline: 1.6612x; 1.6612x over previous
//
#include <hip/hip_runtime.h>
#include <hip/hip_bf16.h>

#define BN_EPS 1e-5f

typedef float f32x4 __attribute__((ext_vector_type(4)));
typedef __bf16 bfx8 __attribute__((ext_vector_type(8)));

// Dims: batch=1024, P=64, B=16, H=64, E=64, D1=512, D2=1024.
// Dead code: softmax over singleton -> aw==1 -> attention MLP + vel emb unused,
// output rows i-independent per group. at-embedding is rank-1:
//   x[r] = 0.05*[h[r], at[r]*S + wa_b],  S[e] = sum_q wa_w[q][e]
//   x@W1 = 0.05*(h@W1top + at[r]*u + v), u = S@W1bot, v = wa_b@W1bot.

// ---------------------------------------------------------------------------
// k0: blocks 0..127 : W2T[n][k] = (bf16)W2[k][n]   (64x64 tiles)
//     blocks 128..135: u[c], v[c]  (8 blocks x 64 cols)
// ---------------------------------------------------------------------------
__global__ __launch_bounds__(256) void k0_prep(
    const float* __restrict__ w2,    // [512,1024]
    const float* __restrict__ w1,    // [128,512]
    const float* __restrict__ wa_w,  // [6,64]
    const float* __restrict__ wa_b,  // [64]
    __bf16* __restrict__ w2t,        // [1024,512] bf16
    float* __restrict__ u_ws,        // [512]
    float* __restrict__ v_ws)        // [512]
{
    const int t = threadIdx.x;
    if (blockIdx.x < 128) {
        __shared__ float tile[64][69];            // pad 69: 2-way max on col reads
        const int bt  = blockIdx.x;
        const int kt0 = (bt & 7) * 64;
        const int n0  = (bt >> 3) * 64;
        #pragma unroll
        for (int i = 0; i < 4; ++i) {
            const int idx = t + i * 256;          // 0..1023
            const int kk  = idx >> 4;             // 0..63
            const int nq  = (idx & 15) * 4;       // 0..60
            const f32x4 val = *(const f32x4*)&w2[(kt0 + kk) * 1024 + n0 + nq];
            #pragma unroll
            for (int j = 0; j < 4; ++j) tile[kk][nq + j] = val[j];
        }
        __syncthreads();
        #pragma unroll
        for (int i = 0; i < 2; ++i) {
            const int idx = t + i * 256;          // 0..511
            const int n   = idx >> 3;             // 0..63
            const int kq  = (idx & 7) * 8;        // 0..56
            bfx8 o;
            #pragma unroll
            for (int j = 0; j < 8; ++j) o[j] = (__bf16)tile[kq + j][n];
            *(bfx8*)&w2t[(n0 + n) * 512 + kt0 + kq] = o;
        }
    } else {
        __shared__ float Sl[64], Wbl[64];
        __shared__ float redu[4][64], redv[4][64];
        const int bu = blockIdx.x - 128;          // 0..7
        if (t < 64) {
            float s = 0.f;
            #pragma unroll
            for (int q = 0; q < 6; ++q) s += wa_w[q * 64 + t];
            Sl[t]  = s;
            Wbl[t] = wa_b[t];
        }
        __syncthreads();
        const int cl   = t & 63;
        const int eseg = t >> 6;
        const int c    = bu * 64 + cl;
        float pu = 0.f, pv = 0.f;
        for (int e = eseg * 16; e < eseg * 16 + 16; ++e) {
            const float w = w1[(64 + e) * 512 + c];
            pu = fmaf(Sl[e], w, pu);
            pv = fmaf(Wbl[e], w, pv);
        }
        redu[eseg][cl] = pu;
        redv[eseg][cl] = pv;
        __syncthreads();
        if (t < 64) {
            u_ws[bu * 64 + t] = redu[0][t] + redu[1][t] + redu[2][t] + redu[3][t];
            v_ws[bu * 64 + t] = redv[0][t] + redv[1][t] + redv[2][t] + redv[3][t];
        }
    }
}

// ---------------------------------------------------------------------------
// k1: p1b[r,c] = (bf16) relu(bn1( 0.05*h[r]@W1top + at[r]*0.05*u + 0.05*v + b1 ))
// 256 blocks x 4 rows, 256 threads x 2 cols, K=64 fp32
// ---------------------------------------------------------------------------
__global__ __launch_bounds__(256) void k1_p1(
    const float* __restrict__ h,     // [1024,64]
    const float* __restrict__ at,    // [1024]
    const float* __restrict__ w1,    // [128,512] (top 64 rows used)
    const float* __restrict__ b1,    // [512]
    const float* __restrict__ bn1,   // [4,512]
    const float* __restrict__ u,     // [512]
    const float* __restrict__ v,     // [512]
    __bf16* __restrict__ p1b)        // [1024,512]
{
    __shared__ float x[4][64];
    const int r0 = blockIdx.x * 4;
    const int t  = threadIdx.x;
    x[t >> 6][t & 63] = 0.05f * h[(r0 + (t >> 6)) * 64 + (t & 63)];
    __syncthreads();

    float acc0[4] = {0.f, 0.f, 0.f, 0.f};
    float acc1[4] = {0.f, 0.f, 0.f, 0.f};
    #pragma unroll 8
    for (int k = 0; k < 64; ++k) {
        const float w0 = w1[k * 512 + t];
        const float wB = w1[k * 512 + t + 256];
        #pragma unroll
        for (int rr = 0; rr < 4; ++rr) {
            const float xv = x[rr][k];
            acc0[rr] = fmaf(xv, w0, acc0[rr]);
            acc1[rr] = fmaf(xv, wB, acc1[rr]);
        }
    }

    float at4[4];
    #pragma unroll
    for (int rr = 0; rr < 4; ++rr) at4[rr] = at[r0 + rr];

    #pragma unroll
    for (int which = 0; which < 2; ++which) {
        const int c = t + which * 256;
        const float uu = 0.05f * u[c];
        const float vv = fmaf(0.05f, v[c], b1[c]);
        const float g  = bn1[c];
        const float be = bn1[512 + c];
        const float mu = bn1[1024 + c];
        const float vr = bn1[1536 + c];
        const float s  = rsqrtf(vr + BN_EPS) * g;
        const float* acc = which ? acc1 : acc0;
        #pragma unroll
        for (int rr = 0; rr < 4; ++rr) {
            const float pre = acc[rr] + fmaf(at4[rr], uu, vv);
            const float val = fmaxf((pre - mu) * s + be, 0.0f);
            p1b[(r0 + rr) * 512 + c] = (__bf16)val;
        }
    }
}

// ---------------------------------------------------------------------------
// k2: MFMA bf16 GEMM [64x512]@[512x64] per block + BN+ReLU+max-pool+broadcast
// grid (cc=16, b=16), 512 threads = 8 waves (4m x 2n), K_tile=128
// ---------------------------------------------------------------------------
__global__ __launch_bounds__(512) void k2_p2_pool(
    const __bf16* __restrict__ p1b,  // [1024,512]
    const __bf16* __restrict__ w2t,  // [1024,512]  (n-major)
    const float* __restrict__ b2,    // [1024]
    const float* __restrict__ bn2,   // [4,1024]
    float* __restrict__ out)         // [1024,1024]
{
    const int cc = blockIdx.x;
    const int b  = blockIdx.y;
    const int t  = threadIdx.x;

    __shared__ __bf16 A_lds[64][136];   // [m][k], pitch 128+8
    __shared__ __bf16 B_lds[64][136];   // [n][k]
    __shared__ float  red[4][64];

    const int wid  = t >> 6;
    const int lane = t & 63;
    const int mw   = wid >> 1;          // 0..3
    const int nw   = wid & 1;           // 0..1
    const int m0   = mw * 16;
    const int n0   = nw * 32;
    const int l15  = lane & 15;
    const int lhi  = lane >> 4;         // 0..3

    f32x4 acc[2] = {};

    for (int kt = 0; kt < 512; kt += 128) {
        #pragma unroll
        for (int i = 0; i < 2; ++i) {
            const int idx = t + i * 512;     // 0..1023
            const int row = idx >> 4;        // 0..63
            const int kq  = (idx & 15) * 8;  // 0..120
            *(f32x4*)&A_lds[row][kq] =
                *(const f32x4*)&p1b[(b * 64 + row) * 512 + kt + kq];
            *(f32x4*)&B_lds[row][kq] =
                *(const f32x4*)&w2t[(cc * 64 + row) * 512 + kt + kq];
        }
        __syncthreads();

        #pragma unroll
        for (int ks = 0; ks < 4; ++ks) {
            const bfx8 a = *(const bfx8*)&A_lds[m0 + l15][ks * 32 + lhi * 8];
            #pragma unroll
            for (int f = 0; f < 2; ++f) {
                const bfx8 bb = *(const bfx8*)&B_lds[n0 + f * 16 + l15][ks * 32 + lhi * 8];
                acc[f] = __builtin_amdgcn_mfma_f32_16x16x32_bf16(a, bb, acc[f], 0, 0, 0);
            }
        }
        __syncthreads();
    }

    // BN + ReLU + per-wave row max (D layout: row=(lane>>4)*4+r, col=lane&15)
    #pragma unroll
    for (int f = 0; f < 2; ++f) {
        const int cg   = cc * 64 + n0 + f * 16 + l15;
        const float s  = rsqrtf(bn2[3072 + cg] + BN_EPS) * bn2[cg];
        const float be = bn2[1024 + cg];
        const float mu = bn2[2048 + cg];
        const float bias = b2[cg];
        float mm = 0.f;  // relu output >= 0
        #pragma unroll
        for (int r = 0; r < 3 + 1; ++r) {
            const float val = (acc[f][r] + bias - mu) * s + be;
            mm = fmaxf(mm, fmaxf(val, 0.f));
        }
        mm = fmaxf(mm, __shfl_xor(mm, 16));
        mm = fmaxf(mm, __shfl_xor(mm, 32));
        if (lane < 16) red[mw][n0 + f * 16 + lane] = mm;
    }
    __syncthreads();

    // pool over 4 m-waves + broadcast to all 64 output rows of the group
    const int cl   = t & 63;
    const int iseg = t >> 6;  // 0..7
    const float pool = fmaxf(fmaxf(red[0][cl], red[1][cl]),
                             fmaxf(red[2][cl], red[3][cl]));
    const int ob = (b * 64 + iseg * 8) * 1024 + cc * 64 + cl;
    #pragma unroll
    for (int ii = 0; ii < 8; ++ii) out[ob + ii * 1024] = pool;
}

extern "C" void kernel_launch(void* const* d_in, const int* in_sizes, int n_in,
                              void* d_out, int out_size, void* d_ws, size_t ws_size,
                              hipStream_t stream) {
    const float* h    = (const float*)d_in[0];   // h_states  [1,1024,64]
    const float* at   = (const float*)d_in[4];   // agent_type[8,1024,1] slice 0
    const float* wa_w = (const float*)d_in[9];   // [6,64]
    const float* wa_b = (const float*)d_in[10];  // [64]
    const float* w1   = (const float*)d_in[17];  // pre1_w [128,512]
    const float* b1   = (const float*)d_in[18];  // pre1_b [512]
    const float* bn1  = (const float*)d_in[19];  // pre_bn1 [4,512]
    const float* w2   = (const float*)d_in[20];  // pre2_w [512,1024]
    const float* b2   = (const float*)d_in[21];  // pre2_b [1024]
    const float* bn2  = (const float*)d_in[22];  // pre_bn2 [4,1024]

    char* ws = (char*)d_ws;
    __bf16* p1b = (__bf16*)ws;                       // 1 MB
    __bf16* w2t = (__bf16*)(ws + (1 << 20));         // 1 MB
    float*  u   = (float*)(ws + (2 << 20));          // 2 KB
    float*  v   = u + 512;
    float*  out = (float*)d_out;

    k0_prep<<<136, 256, 0, stream>>>(w2, w1, wa_w, wa_b, w2t, u, v);
    k1_p1<<<256, 256, 0, stream>>>(h, at, w1, b1, bn1, u, v, p1b);
    k2_p2_pool<<<dim3(16, 16), 512, 0, stream>>>(p1b, w2t, b2, bn2, out);
}

// Round 3
// 21.059 us; speedup vs baseline: 1.6981x; 1.0222x over previous
//
#include <hip/hip_runtime.h>
#include <hip/hip_bf16.h>

#define BN_EPS 1e-5f

typedef float f32x4 __attribute__((ext_vector_type(4)));
typedef __bf16 bfx8 __attribute__((ext_vector_type(8)));

// Dims: batch=1024, P=64, B=16, H=64, E=64, D1=512, D2=1024.
// Dead code: softmax over singleton -> aw==1 -> attention MLP + vel emb unused;
// output rows i-independent per group -> compute once per group, broadcast.
//   x[r] = 0.05*[h[r], at[r]*S + wa_b],  S[e] = sum_q wa_w[q][e]  (128 feats)
//   p1 = relu(bn1(x@W1+b1)); p2 = relu(bn2(p1@W2+b2)); out = max over group rows.

// ---------------------------------------------------------------------------
// k0: transpose+convert W2 [512,1024]->w2t[1024][512]bf16 (blocks 0..127)
//     and W1 [128,512]->w1t[512][128]bf16 (blocks 128..143), 64x64 tiles
// ---------------------------------------------------------------------------
__global__ __launch_bounds__(256) void k0_prep(
    const float* __restrict__ w2, const float* __restrict__ w1,
    __bf16* __restrict__ w2t, __bf16* __restrict__ w1t)
{
    __shared__ float tile[64][69];            // pad: column reads ~2-way max
    const int t = threadIdx.x;
    int kt0, n0, src_ld, dst_ld;
    const float* src;
    __bf16* dst;
    if (blockIdx.x < 128) {
        kt0 = (blockIdx.x & 7) * 64;  n0 = (blockIdx.x >> 3) * 64;
        src = w2; src_ld = 1024; dst = w2t; dst_ld = 512;
    } else {
        const int bt = blockIdx.x - 128;
        kt0 = (bt & 1) * 64;  n0 = (bt >> 1) * 64;
        src = w1; src_ld = 512; dst = w1t; dst_ld = 128;
    }
    #pragma unroll
    for (int i = 0; i < 4; ++i) {
        const int idx = t + i * 256;          // 0..1023
        const int kk  = idx >> 4;             // 0..63
        const int nq  = (idx & 15) * 4;       // 0..60
        const f32x4 val = *(const f32x4*)&src[(size_t)(kt0 + kk) * src_ld + n0 + nq];
        #pragma unroll
        for (int j = 0; j < 4; ++j) tile[kk][nq + j] = val[j];
    }
    __syncthreads();
    #pragma unroll
    for (int i = 0; i < 2; ++i) {
        const int idx = t + i * 256;          // 0..511
        const int n   = idx >> 3;             // 0..63
        const int kq  = (idx & 7) * 8;        // 0..56
        bfx8 o;
        #pragma unroll
        for (int j = 0; j < 8; ++j) o[j] = (__bf16)tile[kq + j][n];
        *(bfx8*)&dst[(size_t)(n0 + n) * dst_ld + kt0 + kq] = o;
    }
}

// ---------------------------------------------------------------------------
// kMain: per block (cc, b): build x -> GEMM1 -> p1 in LDS -> GEMM2 -> pool.
// 512 threads = 8 waves. LDS ~148 KB -> 1 block/CU.
// ---------------------------------------------------------------------------
__global__ __launch_bounds__(512, 2) void kmain(
    const float* __restrict__ h,     // [1024,64]
    const float* __restrict__ at,    // [1024] (agent_type[0])
    const float* __restrict__ wa_w,  // [6,64]
    const float* __restrict__ wa_b,  // [64]
    const __bf16* __restrict__ w1t,  // [512][128]
    const float* __restrict__ b1,    // [512]
    const float* __restrict__ bn1,   // [4,512]
    const __bf16* __restrict__ w2t,  // [1024][512]
    const float* __restrict__ b2,    // [1024]
    const float* __restrict__ bn2,   // [4,1024]
    float* __restrict__ out)         // [1024,1024]
{
    const int cc   = blockIdx.x;
    const int b    = blockIdx.y;
    const int t    = threadIdx.x;
    const int wid  = t >> 6;
    const int lane = t & 63;
    const int l15  = lane & 15;
    const int lhi  = lane >> 4;

    __shared__ __bf16 x_lds[64][136];    // [agent][feat], pitch 136 (2-way max)
    __shared__ __bf16 p1_lds[64][520];   // [agent][c], pitch 520 (2-way max)
    __shared__ __bf16 B2_lds[64][520];   // [n][k], pitch 520
    __shared__ float  red[4][64];        // reused: S during x-build, pool later

    // --- 1. issue B2 panel loads early (T14 async-stage): w2t rows cc*64..+64
    f32x4 b2stage[8];
    {
        const char* base = (const char*)w2t + (size_t)(cc * 64) * 1024;
        #pragma unroll
        for (int i = 0; i < 8; ++i) {
            const int n = i * 8 + wid;       // each wave: one full 1KB row
            b2stage[i] = *(const f32x4*)(base + (size_t)n * 1024 + lane * 16);
        }
    }

    // --- 2. S[e] = sum_q wa_w[q][e]  (into red[0], consumed before epilogue)
    if (t < 64) {
        float s = 0.f;
        #pragma unroll
        for (int q = 0; q < 6; ++q) s += wa_w[q * 64 + t];
        red[0][t] = s;
    }
    __syncthreads();

    // --- 3. build x (bf16) in LDS
    #pragma unroll
    for (int i = 0; i < 2; ++i) {
        const int idx = t + i * 512;         // 0..1023
        const int rr  = idx >> 4;            // 0..63
        const int cg  = (idx & 15) * 8;      // 0..120
        bfx8 o;
        if (cg < 64) {
            const f32x4 v0 = *(const f32x4*)&h[(size_t)(b * 64 + rr) * 64 + cg];
            const f32x4 v1 = *(const f32x4*)&h[(size_t)(b * 64 + rr) * 64 + cg + 4];
            #pragma unroll
            for (int j = 0; j < 4; ++j) {
                o[j]     = (__bf16)(0.05f * v0[j]);
                o[4 + j] = (__bf16)(0.05f * v1[j]);
            }
        } else {
            const float a = at[b * 64 + rr];
            #pragma unroll
            for (int j = 0; j < 8; ++j) {
                const int e = cg - 64 + j;
                o[j] = (__bf16)(0.05f * fmaf(a, red[0][e], wa_b[e]));
            }
        }
        *(bfx8*)&x_lds[rr][cg] = o;
    }
    __syncthreads();

    // --- 4. GEMM1: [64 x 128] @ [128 x 512], wave wid owns n-chunk wid*64
    const int n0w = wid * 64;
    bfx8 b1r[16];                            // all B1 fragments up-front (L2)
    #pragma unroll
    for (int ks = 0; ks < 4; ++ks)
        #pragma unroll
        for (int nf = 0; nf < 4; ++nf)
            b1r[ks * 4 + nf] = *(const bfx8*)(w1t +
                (size_t)(n0w + nf * 16 + l15) * 128 + ks * 32 + lhi * 8);

    f32x4 acc1[4][4] = {};
    #pragma unroll
    for (int ks = 0; ks < 4; ++ks) {
        bfx8 a[4];
        #pragma unroll
        for (int mf = 0; mf < 4; ++mf)
            a[mf] = *(const bfx8*)&x_lds[mf * 16 + l15][ks * 32 + lhi * 8];
        #pragma unroll
        for (int mf = 0; mf < 4; ++mf)
            #pragma unroll
            for (int nf = 0; nf < 4; ++nf)
                acc1[mf][nf] = __builtin_amdgcn_mfma_f32_16x16x32_bf16(
                    a[mf], b1r[ks * 4 + nf], acc1[mf][nf], 0, 0, 0);
    }

    // --- 5. epilogue1: BN1+ReLU -> p1_lds (bf16). C: row=lhi*4+r, col=l15
    #pragma unroll
    for (int nf = 0; nf < 4; ++nf) {
        const int c    = n0w + nf * 16 + l15;
        const float s  = rsqrtf(bn1[1536 + c] + BN_EPS) * bn1[c];
        const float be = bn1[512 + c];
        const float mu = bn1[1024 + c];
        const float bias = b1[c];
        #pragma unroll
        for (int mf = 0; mf < 4; ++mf)
            #pragma unroll
            for (int r = 0; r < 4; ++r) {
                const float val =
                    fmaxf((acc1[mf][nf][r] + bias - mu) * s + be, 0.f);
                p1_lds[mf * 16 + lhi * 4 + r][c] = (__bf16)val;
            }
    }

    // --- 6. land B2 panel into LDS (row-linear within padded pitch)
    #pragma unroll
    for (int i = 0; i < 8; ++i) {
        const int n = i * 8 + wid;
        *(f32x4*)((char*)&B2_lds[0][0] + (size_t)n * 1040 + lane * 16) =
            b2stage[i];
    }
    __syncthreads();

    // --- 7. GEMM2: [64 x 512] @ [512 x 64], waves (mw 4) x (nw 2)
    const int mw = wid >> 1;
    const int nw = wid & 1;
    f32x4 acc2[2] = {};
    #pragma unroll
    for (int ks = 0; ks < 16; ++ks) {
        const bfx8 a = *(const bfx8*)&p1_lds[mw * 16 + l15][ks * 32 + lhi * 8];
        #pragma unroll
        for (int f = 0; f < 2; ++f) {
            const bfx8 bb =
                *(const bfx8*)&B2_lds[nw * 32 + f * 16 + l15][ks * 32 + lhi * 8];
            acc2[f] = __builtin_amdgcn_mfma_f32_16x16x32_bf16(a, bb, acc2[f], 0, 0, 0);
        }
    }

    // --- 8. BN2+ReLU+row-max, pool over waves, broadcast store
    #pragma unroll
    for (int f = 0; f < 2; ++f) {
        const int cg   = cc * 64 + nw * 32 + f * 16 + l15;
        const float s  = rsqrtf(bn2[3072 + cg] + BN_EPS) * bn2[cg];
        const float be = bn2[1024 + cg];
        const float mu = bn2[2048 + cg];
        const float bias = b2[cg];
        float mm = 0.f;                      // relu output >= 0
        #pragma unroll
        for (int r = 0; r < 4; ++r) {
            const float val = (acc2[f][r] + bias - mu) * s + be;
            mm = fmaxf(mm, fmaxf(val, 0.f));
        }
        mm = fmaxf(mm, __shfl_xor(mm, 16));
        mm = fmaxf(mm, __shfl_xor(mm, 32));
        if (lane < 16) red[mw][nw * 32 + f * 16 + lane] = mm;
    }
    __syncthreads();

    const int cl   = t & 63;
    const int iseg = t >> 6;                 // 0..7
    const float pool = fmaxf(fmaxf(red[0][cl], red[1][cl]),
                             fmaxf(red[2][cl], red[3][cl]));
    const int ob = (b * 64 + iseg * 8) * 1024 + cc * 64 + cl;
    #pragma unroll
    for (int ii = 0; ii < 8; ++ii) out[ob + ii * 1024] = pool;
}

extern "C" void kernel_launch(void* const* d_in, const int* in_sizes, int n_in,
                              void* d_out, int out_size, void* d_ws, size_t ws_size,
                              hipStream_t stream) {
    const float* h    = (const float*)d_in[0];   // h_states  [1,1024,64]
    const float* at   = (const float*)d_in[4];   // agent_type[8,1024,1] slice 0
    const float* wa_w = (const float*)d_in[9];   // [6,64]
    const float* wa_b = (const float*)d_in[10];  // [64]
    const float* w1   = (const float*)d_in[17];  // pre1_w [128,512]
    const float* b1   = (const float*)d_in[18];  // pre1_b [512]
    const float* bn1  = (const float*)d_in[19];  // pre_bn1 [4,512]
    const float* w2   = (const float*)d_in[20];  // pre2_w [512,1024]
    const float* b2   = (const float*)d_in[21];  // pre2_b [1024]
    const float* bn2  = (const float*)d_in[22];  // pre_bn2 [4,1024]

    char* ws = (char*)d_ws;
    __bf16* w2t = (__bf16*)ws;                   // 1 MB
    __bf16* w1t = (__bf16*)(ws + (1 << 20));     // 128 KB
    float*  out = (float*)d_out;

    k0_prep<<<144, 256, 0, stream>>>(w2, w1, w2t, w1t);
    kmain<<<dim3(16, 16), 512, 0, stream>>>(h, at, wa_w, wa_b,
                                            w1t, b1, bn1, w2t, b2, bn2, out);
}

// Round 4
// 19.642 us; speedup vs baseline: 1.8206x; 1.0721x over previous
//
#include <hip/hip_runtime.h>
#include <hip/hip_bf16.h>

#define BN_EPS 1e-5f

typedef float f32x4 __attribute__((ext_vector_type(4)));
typedef __bf16 bfx8 __attribute__((ext_vector_type(8)));
typedef __bf16 bfx4 __attribute__((ext_vector_type(4)));

// Dims: batch=1024, P=64, B=16, H=64, E=64, D1=512, D2=1024.
// Dead code: softmax over singleton -> aw==1 -> attention MLP + vel emb unused;
// output rows i-independent per group -> compute once per group, broadcast.
// x[r] = 0.05*[h[r], at[r]*S + wa_b]; p1 = relu(x@W1*sc1+sh1);
// p2 = relu(p1@W2*sc2+sh2); out[b*64+i] = max over group rows of p2.

// ---------------------------------------------------------------------------
// k0: blocks 0..127  : w2t[1024][512] = (bf16) W2^T
//     blocks 128..143: w1t[512][128]  = (bf16) W1^T
//     blocks 144..159: xg[1024][128]  = (bf16) 0.05*[h | at*S + wa_b]
//     block  160     : scsh = {sc1[512], sh1[512], sc2[1024], sh2[1024]}
// ---------------------------------------------------------------------------
__global__ __launch_bounds__(256) void k0_prep(
    const float* __restrict__ w2, const float* __restrict__ w1,
    const float* __restrict__ h, const float* __restrict__ at,
    const float* __restrict__ wa_w, const float* __restrict__ wa_b,
    const float* __restrict__ b1, const float* __restrict__ bn1,
    const float* __restrict__ b2, const float* __restrict__ bn2,
    __bf16* __restrict__ w2t, __bf16* __restrict__ w1t,
    __bf16* __restrict__ xg, float* __restrict__ scsh)
{
    const int t  = threadIdx.x;
    const int bx = blockIdx.x;

    if (bx < 144) {                       // transposes
        __shared__ float tile[64][69];
        int kt0, n0, src_ld, dst_ld;
        const float* src;
        __bf16* dst;
        if (bx < 128) {
            kt0 = (bx & 7) * 64;  n0 = (bx >> 3) * 64;
            src = w2; src_ld = 1024; dst = w2t; dst_ld = 512;
        } else {
            const int bt = bx - 128;
            kt0 = (bt & 1) * 64;  n0 = (bt >> 1) * 64;
            src = w1; src_ld = 512; dst = w1t; dst_ld = 128;
        }
        #pragma unroll
        for (int i = 0; i < 4; ++i) {
            const int idx = t + i * 256;
            const int kk  = idx >> 4;
            const int nq  = (idx & 15) * 4;
            const f32x4 val = *(const f32x4*)&src[(size_t)(kt0 + kk) * src_ld + n0 + nq];
            #pragma unroll
            for (int j = 0; j < 4; ++j) tile[kk][nq + j] = val[j];
        }
        __syncthreads();
        #pragma unroll
        for (int i = 0; i < 2; ++i) {
            const int idx = t + i * 256;
            const int n   = idx >> 3;
            const int kq  = (idx & 7) * 8;
            bfx8 o;
            #pragma unroll
            for (int j = 0; j < 8; ++j) o[j] = (__bf16)tile[kq + j][n];
            *(bfx8*)&dst[(size_t)(n0 + n) * dst_ld + kt0 + kq] = o;
        }
    } else if (bx < 160) {                // xg build
        __shared__ float S[64];
        const int r0 = (bx - 144) * 64;
        if (t < 64) {
            float s = 0.f;
            #pragma unroll
            for (int q = 0; q < 6; ++q) s += wa_w[q * 64 + t];
            S[t] = s;
        }
        __syncthreads();
        #pragma unroll
        for (int i = 0; i < 4; ++i) {
            const int idx = t + i * 256;          // 0..1023 bfx8 slots
            const int row = idx >> 4;
            const int cg  = (idx & 15) * 8;
            bfx8 o;
            if (cg < 64) {
                const f32x4 v0 = *(const f32x4*)&h[(size_t)(r0 + row) * 64 + cg];
                const f32x4 v1 = *(const f32x4*)&h[(size_t)(r0 + row) * 64 + cg + 4];
                #pragma unroll
                for (int j = 0; j < 4; ++j) {
                    o[j]     = (__bf16)(0.05f * v0[j]);
                    o[4 + j] = (__bf16)(0.05f * v1[j]);
                }
            } else {
                const float a = at[r0 + row];
                #pragma unroll
                for (int j = 0; j < 8; ++j) {
                    const int e = cg - 64 + j;
                    o[j] = (__bf16)(0.05f * fmaf(a, S[e], wa_b[e]));
                }
            }
            *(bfx8*)&xg[(size_t)(r0 + row) * 128 + cg] = o;
        }
    } else {                              // scale/shift folding
        for (int c = t; c < 512; c += 256) {
            const float s = rsqrtf(bn1[1536 + c] + BN_EPS) * bn1[c];
            scsh[c]       = s;
            scsh[512 + c] = (b1[c] - bn1[1024 + c]) * s + bn1[512 + c];
        }
        for (int c = t; c < 1024; c += 256) {
            const float s  = rsqrtf(bn2[3072 + c] + BN_EPS) * bn2[c];
            scsh[1024 + c] = s;
            scsh[2048 + c] = (b2[c] - bn2[2048 + c]) * s + bn2[1024 + c];
        }
    }
}

// ---------------------------------------------------------------------------
// kmain: per block (cc, b): GEMM1 (swapped, D1[c][m]) -> p1 in LDS (b64 writes)
//        -> GEMM2 (D2[m][n]) -> max-pool over m -> broadcast store.
// 512 threads = 8 waves. LDS ~152 KB -> 1 block/CU.
// ---------------------------------------------------------------------------
__global__ __launch_bounds__(512, 2) void kmain(
    const __bf16* __restrict__ xg,   // [1024][128]
    const __bf16* __restrict__ w1t,  // [512][128]
    const __bf16* __restrict__ w2t,  // [1024][512]
    const float* __restrict__ scsh,  // sc1,sh1,sc2,sh2
    float* __restrict__ out)         // [1024,1024]
{
    const int cc   = blockIdx.x;
    const int b    = blockIdx.y;
    const int t    = threadIdx.x;
    const int wid  = t >> 6;
    const int lane = t & 63;
    const int l15  = lane & 15;
    const int lhi  = lane >> 4;

    __shared__ __bf16 x_lds[64][136];    // [m][k]   (pitch 272B: 2-way banks)
    __shared__ __bf16 p1_lds[64][520];   // [m][c]   (pitch 1040B: 2-way banks)
    __shared__ __bf16 B2_lds[64][520];   // [n][k]
    __shared__ float  red[4][64];

    // --- 1. early-issue B2 panel (w2t rows cc*64..+64), 1 row per wave per i
    f32x4 b2stage[8];
    {
        const __bf16* base = w2t + (size_t)(cc * 64) * 512;
        #pragma unroll
        for (int i = 0; i < 8; ++i) {
            const int n = i * 8 + wid;
            b2stage[i] = *(const f32x4*)(base + (size_t)n * 512 + lane * 8);
        }
    }

    // --- 2. stage x tile (16 KB, vectorized)
    #pragma unroll
    for (int i = 0; i < 2; ++i) {
        const int idx = t + i * 512;         // 0..1023 bfx8 slots
        const int row = idx >> 4;
        const int cg  = (idx & 15) * 8;
        *(bfx8*)&x_lds[row][cg] =
            *(const bfx8*)&xg[(size_t)(b * 64 + row) * 128 + cg];
    }
    __syncthreads();

    // --- 3. GEMM1 swapped: D1[c][m]; wave owns c-chunk wid*64
    const int c0w = wid * 64;
    f32x4 acc1[4][4] = {};                   // [cf][mf]
    #pragma unroll
    for (int ks = 0; ks < 4; ++ks) {
        bfx8 af[4];
        #pragma unroll
        for (int cf = 0; cf < 4; ++cf)
            af[cf] = *(const bfx8*)&w1t[(size_t)(c0w + cf * 16 + l15) * 128 +
                                        ks * 32 + lhi * 8];
        bfx8 bf_[4];
        #pragma unroll
        for (int mf = 0; mf < 4; ++mf)
            bf_[mf] = *(const bfx8*)&x_lds[mf * 16 + l15][ks * 32 + lhi * 8];
        #pragma unroll
        for (int cf = 0; cf < 4; ++cf)
            #pragma unroll
            for (int mf = 0; mf < 4; ++mf)
                acc1[cf][mf] = __builtin_amdgcn_mfma_f32_16x16x32_bf16(
                    af[cf], bf_[mf], acc1[cf][mf], 0, 0, 0);
    }

    // --- 4. epilogue1: thread holds 4 consecutive c per (cf,mf) -> b64 writes
    {
        f32x4 sc[4], sh[4];
        #pragma unroll
        for (int cf = 0; cf < 4; ++cf) {
            const int c4 = c0w + cf * 16 + lhi * 4;
            sc[cf] = *(const f32x4*)&scsh[c4];
            sh[cf] = *(const f32x4*)&scsh[512 + c4];
        }
        #pragma unroll
        for (int cf = 0; cf < 4; ++cf)
            #pragma unroll
            for (int mf = 0; mf < 4; ++mf) {
                bfx4 pk;
                #pragma unroll
                for (int r = 0; r < 4; ++r)
                    pk[r] = (__bf16)fmaxf(
                        fmaf(acc1[cf][mf][r], sc[cf][r], sh[cf][r]), 0.f);
                *(bfx4*)&p1_lds[mf * 16 + l15][c0w + cf * 16 + lhi * 4] = pk;
            }
    }

    // --- 5. land B2 panel
    #pragma unroll
    for (int i = 0; i < 8; ++i) {
        const int n = i * 8 + wid;
        *(f32x4*)((char*)&B2_lds[0][0] + (size_t)n * 1040 + lane * 16) =
            b2stage[i];
    }
    __syncthreads();

    // --- 6. GEMM2: D2[m][n]; wave: mf = wid>>1, n-half = wid&1 (no dup)
    const int mrow  = (wid >> 1) * 16;
    const int nbase = (wid & 1) * 32;
    f32x4 acc2[2] = {};
    #pragma unroll
    for (int ks = 0; ks < 16; ++ks) {
        const bfx8 a = *(const bfx8*)&p1_lds[mrow + l15][ks * 32 + lhi * 8];
        #pragma unroll
        for (int nf = 0; nf < 2; ++nf) {
            const bfx8 bb =
                *(const bfx8*)&B2_lds[nbase + nf * 16 + l15][ks * 32 + lhi * 8];
            acc2[nf] = __builtin_amdgcn_mfma_f32_16x16x32_bf16(a, bb, acc2[nf], 0, 0, 0);
        }
    }

    // --- 7. epilogue2 + pool over m (rows): in-thread r, shfl over lhi
    #pragma unroll
    for (int nf = 0; nf < 2; ++nf) {
        const int ng  = cc * 64 + nbase + nf * 16 + l15;
        const float s2 = scsh[1024 + ng];
        const float h2 = scsh[2048 + ng];
        float mm = 0.f;                      // relu >= 0
        #pragma unroll
        for (int r = 0; r < 4; ++r)
            mm = fmaxf(mm, fmaxf(fmaf(acc2[nf][r], s2, h2), 0.f));
        mm = fmaxf(mm, __shfl_xor(mm, 16));
        mm = fmaxf(mm, __shfl_xor(mm, 32));
        if (lane < 16) red[wid >> 1][nbase + nf * 16 + lane] = mm;
    }
    __syncthreads();

    // --- 8. final pool over 4 m-frags + broadcast store (vectorized)
    #pragma unroll
    for (int i = 0; i < 2; ++i) {
        const int q   = t + i * 512;         // 0..1023 f32x4 slots
        const int row = q >> 4;
        const int cq  = (q & 15) * 4;
        const f32x4 r0 = *(const f32x4*)&red[0][cq];
        const f32x4 r1 = *(const f32x4*)&red[1][cq];
        const f32x4 r2 = *(const f32x4*)&red[2][cq];
        const f32x4 r3 = *(const f32x4*)&red[3][cq];
        f32x4 pv;
        #pragma unroll
        for (int j = 0; j < 4; ++j)
            pv[j] = fmaxf(fmaxf(r0[j], r1[j]), fmaxf(r2[j], r3[j]));
        *(f32x4*)&out[(size_t)(b * 64 + row) * 1024 + cc * 64 + cq] = pv;
    }
}

extern "C" void kernel_launch(void* const* d_in, const int* in_sizes, int n_in,
                              void* d_out, int out_size, void* d_ws, size_t ws_size,
                              hipStream_t stream) {
    const float* h    = (const float*)d_in[0];   // h_states  [1,1024,64]
    const float* at   = (const float*)d_in[4];   // agent_type[8,1024,1] slice 0
    const float* wa_w = (const float*)d_in[9];   // [6,64]
    const float* wa_b = (const float*)d_in[10];  // [64]
    const float* w1   = (const float*)d_in[17];  // pre1_w [128,512]
    const float* b1   = (const float*)d_in[18];  // pre1_b [512]
    const float* bn1  = (const float*)d_in[19];  // pre_bn1 [4,512]
    const float* w2   = (const float*)d_in[20];  // pre2_w [512,1024]
    const float* b2   = (const float*)d_in[21];  // pre2_b [1024]
    const float* bn2  = (const float*)d_in[22];  // pre_bn2 [4,1024]

    char* ws = (char*)d_ws;
    __bf16* w2t = (__bf16*)ws;                        // 1 MB
    __bf16* w1t = (__bf16*)(ws + (1 << 20));          // 128 KB
    __bf16* xg  = (__bf16*)(ws + (1 << 20) + (128 << 10));   // 256 KB
    float*  scsh = (float*)(ws + (1 << 20) + (384 << 10));   // 12 KB
    float*  out  = (float*)d_out;

    k0_prep<<<161, 256, 0, stream>>>(w2, w1, h, at, wa_w, wa_b,
                                     b1, bn1, b2, bn2, w2t, w1t, xg, scsh);
    kmain<<<dim3(16, 16), 512, 0, stream>>>(xg, w1t, w2t, scsh, out);
}

// Round 5
// 19.038 us; speedup vs baseline: 1.8783x; 1.0317x over previous
//
#include <hip/hip_runtime.h>
#include <hip/hip_bf16.h>

#define BN_EPS 1e-5f

typedef float f32x4 __attribute__((ext_vector_type(4)));
typedef __bf16 bfx8 __attribute__((ext_vector_type(8)));
typedef __bf16 bfx4 __attribute__((ext_vector_type(4)));

// Dims: batch=1024, P=64, B=16, H=64, E=64, D1=512, D2=1024.
// Dead code: softmax over singleton -> aw==1 -> attention MLP + vel emb unused;
// output rows i-independent per group -> compute once per group, broadcast.
// x[r] = 0.05*[h[r], at[r]*S + wa_b]; p1 = relu(x@W1*sc1+sh1);
// p2 = relu(p1@W2*sc2+sh2); out[b*64+i] = max over group rows of p2.

// ---------------------------------------------------------------------------
// k0: blocks 0..127  : w2t[1024][512] = (bf16) W2^T
//     blocks 128..143: w1t[512][128]  = (bf16) W1^T
//     blocks 144..159: xg[1024][128]  = (bf16) 0.05*[h | at*S + wa_b]
//     block  160     : scsh = {sc1[512], sh1[512], sc2[1024], sh2[1024]}
// ---------------------------------------------------------------------------
__global__ __launch_bounds__(256) void k0_prep(
    const float* __restrict__ w2, const float* __restrict__ w1,
    const float* __restrict__ h, const float* __restrict__ at,
    const float* __restrict__ wa_w, const float* __restrict__ wa_b,
    const float* __restrict__ b1, const float* __restrict__ bn1,
    const float* __restrict__ b2, const float* __restrict__ bn2,
    __bf16* __restrict__ w2t, __bf16* __restrict__ w1t,
    __bf16* __restrict__ xg, float* __restrict__ scsh)
{
    const int t  = threadIdx.x;
    const int bx = blockIdx.x;

    if (bx < 144) {                       // transposes
        __shared__ float tile[64][69];
        int kt0, n0, src_ld, dst_ld;
        const float* src;
        __bf16* dst;
        if (bx < 128) {
            kt0 = (bx & 7) * 64;  n0 = (bx >> 3) * 64;
            src = w2; src_ld = 1024; dst = w2t; dst_ld = 512;
        } else {
            const int bt = bx - 128;
            kt0 = (bt & 1) * 64;  n0 = (bt >> 1) * 64;
            src = w1; src_ld = 512; dst = w1t; dst_ld = 128;
        }
        #pragma unroll
        for (int i = 0; i < 4; ++i) {
            const int idx = t + i * 256;
            const int kk  = idx >> 4;
            const int nq  = (idx & 15) * 4;
            const f32x4 val = *(const f32x4*)&src[(size_t)(kt0 + kk) * src_ld + n0 + nq];
            #pragma unroll
            for (int j = 0; j < 4; ++j) tile[kk][nq + j] = val[j];
        }
        __syncthreads();
        #pragma unroll
        for (int i = 0; i < 2; ++i) {
            const int idx = t + i * 256;
            const int n   = idx >> 3;
            const int kq  = (idx & 7) * 8;
            bfx8 o;
            #pragma unroll
            for (int j = 0; j < 8; ++j) o[j] = (__bf16)tile[kq + j][n];
            *(bfx8*)&dst[(size_t)(n0 + n) * dst_ld + kt0 + kq] = o;
        }
    } else if (bx < 160) {                // xg build
        __shared__ float S[64];
        const int r0 = (bx - 144) * 64;
        if (t < 64) {
            float s = 0.f;
            #pragma unroll
            for (int q = 0; q < 6; ++q) s += wa_w[q * 64 + t];
            S[t] = s;
        }
        __syncthreads();
        #pragma unroll
        for (int i = 0; i < 4; ++i) {
            const int idx = t + i * 256;          // 0..1023 bfx8 slots
            const int row = idx >> 4;
            const int cg  = (idx & 15) * 8;
            bfx8 o;
            if (cg < 64) {
                const f32x4 v0 = *(const f32x4*)&h[(size_t)(r0 + row) * 64 + cg];
                const f32x4 v1 = *(const f32x4*)&h[(size_t)(r0 + row) * 64 + cg + 4];
                #pragma unroll
                for (int j = 0; j < 4; ++j) {
                    o[j]     = (__bf16)(0.05f * v0[j]);
                    o[4 + j] = (__bf16)(0.05f * v1[j]);
                }
            } else {
                const float a = at[r0 + row];
                #pragma unroll
                for (int j = 0; j < 8; ++j) {
                    const int e = cg - 64 + j;
                    o[j] = (__bf16)(0.05f * fmaf(a, S[e], wa_b[e]));
                }
            }
            *(bfx8*)&xg[(size_t)(r0 + row) * 128 + cg] = o;
        }
    } else {                              // scale/shift folding
        for (int c = t; c < 512; c += 256) {
            const float s = rsqrtf(bn1[1536 + c] + BN_EPS) * bn1[c];
            scsh[c]       = s;
            scsh[512 + c] = (b1[c] - bn1[1024 + c]) * s + bn1[512 + c];
        }
        for (int c = t; c < 1024; c += 256) {
            const float s  = rsqrtf(bn2[3072 + c] + BN_EPS) * bn2[c];
            scsh[1024 + c] = s;
            scsh[2048 + c] = (b2[c] - bn2[2048 + c]) * s + bn2[1024 + c];
        }
    }
}

// ---------------------------------------------------------------------------
// kmain: per block (cc, b): GEMM1 (swapped, D1[c][m]) -> p1 in LDS
//        -> GEMM2 (D2[m][n]) -> max-pool over m -> broadcast store.
// 512 threads = 8 waves. LDS ~148 KB -> 1 block/CU.
// Load schedule: {x, b1r} issued pre-barrier-1 (drained by its vmcnt(0));
// {b2stage, sc1/sh1} issued post-barrier-1, hidden under GEMM1, drained at
// barrier-2 right when needed.
// ---------------------------------------------------------------------------
__global__ __launch_bounds__(512, 2) void kmain(
    const __bf16* __restrict__ xg,   // [1024][128]
    const __bf16* __restrict__ w1t,  // [512][128]
    const __bf16* __restrict__ w2t,  // [1024][512]
    const float* __restrict__ scsh,  // sc1,sh1,sc2,sh2
    float* __restrict__ out)         // [1024,1024]
{
    const int cc   = blockIdx.x;
    const int b    = blockIdx.y;
    const int t    = threadIdx.x;
    const int wid  = t >> 6;
    const int lane = t & 63;
    const int l15  = lane & 15;
    const int lhi  = lane >> 4;
    const int c0w  = wid * 64;

    __shared__ __bf16 x_lds[64][136];    // [m][k]
    __shared__ __bf16 p1_lds[64][520];   // [m][c]
    __shared__ __bf16 B2_lds[64][520];   // [n][k]
    __shared__ float  red[4][64];

    // --- Phase 0: issue x (first), then b1r (W1T fragments); write x; barrier.
    bfx8 xfrag[2];
    #pragma unroll
    for (int i = 0; i < 2; ++i) {
        const int idx = t + i * 512;
        const int row = idx >> 4;
        const int cg  = (idx & 15) * 8;
        xfrag[i] = *(const bfx8*)&xg[(size_t)(b * 64 + row) * 128 + cg];
    }
    bfx8 b1r[16];
    #pragma unroll
    for (int ks = 0; ks < 4; ++ks)
        #pragma unroll
        for (int cf = 0; cf < 4; ++cf)
            b1r[ks * 4 + cf] = *(const bfx8*)&w1t[
                (size_t)(c0w + cf * 16 + l15) * 128 + ks * 32 + lhi * 8];
    #pragma unroll
    for (int i = 0; i < 2; ++i) {
        const int idx = t + i * 512;
        const int row = idx >> 4;
        const int cg  = (idx & 15) * 8;
        *(bfx8*)&x_lds[row][cg] = xfrag[i];
    }
    __syncthreads();

    // --- Phase 1: issue B2 panel + epilogue-1 params (hide under GEMM1)
    f32x4 b2stage[8];
    {
        const __bf16* base = w2t + (size_t)(cc * 64) * 512;
        #pragma unroll
        for (int i = 0; i < 8; ++i) {
            const int n = i * 8 + wid;
            b2stage[i] = *(const f32x4*)(base + (size_t)n * 512 + lane * 8);
        }
    }
    f32x4 sc[4], sh[4];
    #pragma unroll
    for (int cf = 0; cf < 4; ++cf) {
        const int c4 = c0w + cf * 16 + lhi * 4;
        sc[cf] = *(const f32x4*)&scsh[c4];
        sh[cf] = *(const f32x4*)&scsh[512 + c4];
    }

    // --- GEMM1 swapped: D1[c][m]; wave owns c-chunk wid*64 (b1r in regs)
    f32x4 acc1[4][4] = {};                   // [cf][mf]
    #pragma unroll
    for (int ks = 0; ks < 4; ++ks) {
        bfx8 bf_[4];
        #pragma unroll
        for (int mf = 0; mf < 4; ++mf)
            bf_[mf] = *(const bfx8*)&x_lds[mf * 16 + l15][ks * 32 + lhi * 8];
        #pragma unroll
        for (int cf = 0; cf < 4; ++cf)
            #pragma unroll
            for (int mf = 0; mf < 4; ++mf)
                acc1[cf][mf] = __builtin_amdgcn_mfma_f32_16x16x32_bf16(
                    b1r[ks * 4 + cf], bf_[mf], acc1[cf][mf], 0, 0, 0);
    }

    // --- land B2 panel (ds pipe), then epilogue-1 (VALU overlaps)
    #pragma unroll
    for (int i = 0; i < 8; ++i) {
        const int n = i * 8 + wid;
        *(f32x4*)((char*)&B2_lds[0][0] + (size_t)n * 1040 + lane * 16) =
            b2stage[i];
    }
    #pragma unroll
    for (int cf = 0; cf < 4; ++cf)
        #pragma unroll
        for (int mf = 0; mf < 4; ++mf) {
            bfx4 pk;
            #pragma unroll
            for (int r = 0; r < 4; ++r)
                pk[r] = (__bf16)fmaxf(
                    fmaf(acc1[cf][mf][r], sc[cf][r], sh[cf][r]), 0.f);
            *(bfx4*)&p1_lds[mf * 16 + l15][c0w + cf * 16 + lhi * 4] = pk;
        }
    __syncthreads();

    // --- GEMM2: D2[m][n]; wave: mrow = (wid>>1)*16, n-half = wid&1
    const int mrow  = (wid >> 1) * 16;
    const int nbase = (wid & 1) * 32;
    float s2[2], h2[2];
    #pragma unroll
    for (int nf = 0; nf < 2; ++nf) {
        const int ng = cc * 64 + nbase + nf * 16 + l15;
        s2[nf] = scsh[1024 + ng];
        h2[nf] = scsh[2048 + ng];
    }
    f32x4 acc2[2] = {};
    #pragma unroll
    for (int ks = 0; ks < 16; ++ks) {
        const bfx8 a = *(const bfx8*)&p1_lds[mrow + l15][ks * 32 + lhi * 8];
        #pragma unroll
        for (int nf = 0; nf < 2; ++nf) {
            const bfx8 bb =
                *(const bfx8*)&B2_lds[nbase + nf * 16 + l15][ks * 32 + lhi * 8];
            acc2[nf] = __builtin_amdgcn_mfma_f32_16x16x32_bf16(a, bb, acc2[nf], 0, 0, 0);
        }
    }

    // --- epilogue-2 + pool over m: in-thread r, shfl over lhi
    #pragma unroll
    for (int nf = 0; nf < 2; ++nf) {
        float mm = 0.f;                      // relu >= 0
        #pragma unroll
        for (int r = 0; r < 4; ++r)
            mm = fmaxf(mm, fmaxf(fmaf(acc2[nf][r], s2[nf], h2[nf]), 0.f));
        mm = fmaxf(mm, __shfl_xor(mm, 16));
        mm = fmaxf(mm, __shfl_xor(mm, 32));
        if (lane < 16) red[wid >> 1][nbase + nf * 16 + lane] = mm;
    }
    __syncthreads();

    // --- final pool over 4 m-frags + broadcast store (vectorized)
    #pragma unroll
    for (int i = 0; i < 2; ++i) {
        const int q   = t + i * 512;
        const int row = q >> 4;
        const int cq  = (q & 15) * 4;
        const f32x4 r0 = *(const f32x4*)&red[0][cq];
        const f32x4 r1 = *(const f32x4*)&red[1][cq];
        const f32x4 r2 = *(const f32x4*)&red[2][cq];
        const f32x4 r3 = *(const f32x4*)&red[3][cq];
        f32x4 pv;
        #pragma unroll
        for (int j = 0; j < 4; ++j)
            pv[j] = fmaxf(fmaxf(r0[j], r1[j]), fmaxf(r2[j], r3[j]));
        *(f32x4*)&out[(size_t)(b * 64 + row) * 1024 + cc * 64 + cq] = pv;
    }
}

extern "C" void kernel_launch(void* const* d_in, const int* in_sizes, int n_in,
                              void* d_out, int out_size, void* d_ws, size_t ws_size,
                              hipStream_t stream) {
    const float* h    = (const float*)d_in[0];   // h_states  [1,1024,64]
    const float* at   = (const float*)d_in[4];   // agent_type[8,1024,1] slice 0
    const float* wa_w = (const float*)d_in[9];   // [6,64]
    const float* wa_b = (const float*)d_in[10];  // [64]
    const float* w1   = (const float*)d_in[17];  // pre1_w [128,512]
    const float* b1   = (const float*)d_in[18];  // pre1_b [512]
    const float* bn1  = (const float*)d_in[19];  // pre_bn1 [4,512]
    const float* w2   = (const float*)d_in[20];  // pre2_w [512,1024]
    const float* b2   = (const float*)d_in[21];  // pre2_b [1024]
    const float* bn2  = (const float*)d_in[22];  // pre_bn2 [4,1024]

    char* ws = (char*)d_ws;
    __bf16* w2t = (__bf16*)ws;                        // 1 MB
    __bf16* w1t = (__bf16*)(ws + (1 << 20));          // 128 KB
    __bf16* xg  = (__bf16*)(ws + (1 << 20) + (128 << 10));   // 256 KB
    float*  scsh = (float*)(ws + (1 << 20) + (384 << 10));   // 12 KB
    float*  out  = (float*)d_out;

    k0_prep<<<161, 256, 0, stream>>>(w2, w1, h, at, wa_w, wa_b,
                                     b1, bn1, b2, bn2, w2t, w1t, xg, scsh);
    kmain<<<dim3(16, 16), 512, 0, stream>>>(xg, w1t, w2t, scsh, out);
}